// Round 2
// baseline (1310.057 us; speedup 1.0000x reference)
//
#include <hip/hip_runtime.h>
#include <math.h>

// Fused Conv2d(64->128,3x3,valid) + bias + min(oc) + tanh(tanh()) via
// bf16 MFMA implicit GEMM (mfma_f32_32x32x16_bf16).
//
// Round 7: B fully register-resident.
//  - All 72 B fragments (36 ksteps x 2 n-tiles, 288 VGPRs/lane) are loaded
//    from L2 BEFORE the x staging loads; their latency hides under the x
//    HBM round. The K-loop has ZERO global loads -> no L2-latency stalls.
//  - A: 3-stage (distance-2) ds_read_b128 pipeline (~120cy LDS latency
//    covered by 2 ksteps of MFMA).
//  - launch_bounds(256,4): VGPR cap 512/wave; peak use ~400. Occupancy
//    still LDS-capped at 4 blocks/CU (135KB/160KB).
//  - Staging (round 6): batched loads, v_cvt_pk_bf16_f32 conversion.
// Block: 256 thr = 4 waves; tile 2 rows x 64 cols x 128 oc.
// LDS: xt[(row4*4+icc)*2+hi][col66][j8] bf16 = 33792 B.
// Epilogue: LDS transpose (sm[128][65] overlay) + row-min + shfl_xor.

typedef __attribute__((ext_vector_type(8))) short bf16x8;
typedef __attribute__((ext_vector_type(16))) float f32x16;

static __device__ __forceinline__ short f2bf(float f) {
    unsigned u = __float_as_uint(f);
    u += 0x7fffu + ((u >> 16) & 1u);
    return (short)(u >> 16);
}

// v_cvt_pk_bf16_f32: D[15:0]=bf16(a), D[31:16]=bf16(b), round-nearest-even.
static __device__ __forceinline__ unsigned cvt_pk_bf16(float a, float b) {
    unsigned r;
    asm("v_cvt_pk_bf16_f32 %0, %1, %2" : "=v"(r) : "v"(a), "v"(b));
    return r;
}

// d_ws layout: bf16 bits, idx = ((kstep*2 + hi)*128 + oc)*8 + j
// kstep = tap*4 + icc, tap = kh*3 + kw, ic = icc*16 + hi*8 + j. 73728 elems.
__global__ void wtrans(const float* __restrict__ wg, short* __restrict__ wsB) {
    int o4 = blockIdx.x * 256 + threadIdx.x;   // 0..18431 (x4 elements)
    if (o4 >= 18432) return;
    float4 v = ((const float4*)wg)[o4];        // coalesced read
    float f[4] = {v.x, v.y, v.z, v.w};
    int base = o4 * 4;
    #pragma unroll
    for (int q = 0; q < 4; ++q) {
        int e  = base + q;                     // ((oc*64+ic)*3+kh)*3+kw
        int kw = e % 3, r1 = e / 3;
        int kh = r1 % 3, r2 = r1 / 3;
        int ic = r2 & 63, oc = r2 >> 6;
        int tap = kh * 3 + kw;
        int icc = ic >> 4, hi = (ic >> 3) & 1, j = ic & 7;
        int kstep = tap * 4 + icc;
        wsB[((kstep * 2 + hi) * 128 + oc) * 8 + j] = f2bf(f[q]);
    }
}

__global__ __launch_bounds__(256, 4)
void conv_min_tanh_mfma(const float* __restrict__ xg,
                        const short* __restrict__ wsB,
                        const float* __restrict__ bg,
                        float* __restrict__ out) {
    __shared__ __align__(16) short xt[16896];  // [32 g][66 col][8 j] = 33792 B

    const int tid  = threadIdx.x;
    const int lane = tid & 63, l31 = lane & 31, hi = lane >> 5;
    const int w    = tid >> 6;
    const int r    = w & 1;        // output row within pair
    const int nh   = w >> 1;       // oc half
    const int ow0  = blockIdx.x * 64;
    const int oh0  = blockIdx.y * 2;
    const int b    = blockIdx.z;

    // ---- B: load ALL 72 fragments to registers (L2-resident; issued first
    // so the latency hides under the x HBM staging below).
    const bf16x8* bbase = (const bf16x8*)(wsB + ((size_t)hi * 128 + nh * 64 + l31) * 8);
    bf16x8 B0[36], B1[36];
    #pragma unroll
    for (int k = 0; k < 36; ++k) {
        B0[k] = bbase[k * 256];
        B1[k] = bbase[k * 256 + 32];
    }

    // ---- stage x: rows oh0..+3, cols ow0..+65, 64 ic -> 2112 bf16x8 vectors
    // Phase A: issue ALL global loads.
    float f[9][8];
    #pragma unroll
    for (int t = 0; t < 9; ++t) {
        int idx = t * 256 + tid;
        if (idx < 2112) {                      // always true for t<8
            int g   = idx / 66;                // (row*4+icc)*2+hi
            int col = idx - g * 66;
            int row = g >> 3;
            int icb = ((g >> 1) & 3) * 16 + (g & 1) * 8;
            int iw  = ow0 + col;
            const float* src = xg + (((size_t)(b * 64 + icb) * 256) + (oh0 + row)) * 256 + iw;
            bool valid = iw < 256;
            #pragma unroll
            for (int j = 0; j < 8; ++j) f[t][j] = valid ? src[j * 65536] : 0.f;
        }
    }
    // Phase B: convert (v_cvt_pk_bf16_f32) + LDS write.
    #pragma unroll
    for (int t = 0; t < 9; ++t) {
        int idx = t * 256 + tid;
        if (idx < 2112) {
            int g   = idx / 66;
            int col = idx - g * 66;
            bf16x8 v;
            unsigned* vp = (unsigned*)&v;
            #pragma unroll
            for (int p = 0; p < 4; ++p)
                vp[p] = cvt_pk_bf16(f[t][2 * p], f[t][2 * p + 1]);
            *(bf16x8*)(xt + g * 528 + col * 8) = v;
        }
    }

    __syncthreads();   // the only K-side barrier

    f32x16 acc00 = {}, acc01 = {}, acc10 = {}, acc11 = {};

    // A pipeline, 3 stages (distance 2).
    // kstep k: tap = k>>2 (kh=tap/3, kw=tap%3), icc = k&3;
    // addr = ((r+kh)*4 + icc)*2 + hi) * 528 + (l31+kw)*8
    const bf16x8* ap0 = (const bf16x8*)(xt + ((r * 4 + 0) * 2 + hi) * 528 + l31 * 8);
    const bf16x8* ap1 = (const bf16x8*)(xt + ((r * 4 + 1) * 2 + hi) * 528 + l31 * 8);
    bf16x8 ac0 = ap0[0], ac1 = ap0[32];   // k=0
    bf16x8 an0 = ap1[0], an1 = ap1[32];   // k=1

    #pragma unroll
    for (int k = 0; k < 36; ++k) {
        // issue A prefetch for k+2 (2 ds_read_b128)
        bf16x8 af0 = an0, af1 = an1;
        if (k < 34) {
            const int kn = k + 2, tapn = kn >> 2, iccn = kn & 3;
            const int khn = tapn / 3, kwn = tapn - khn * 3;
            const bf16x8* apn = (const bf16x8*)(xt +
                (((r + khn) * 4 + iccn) * 2 + hi) * 528 + (l31 + kwn) * 8);
            af0 = apn[0];
            af1 = apn[32];
        }
        acc00 = __builtin_amdgcn_mfma_f32_32x32x16_bf16(ac0, B0[k], acc00, 0, 0, 0);
        acc01 = __builtin_amdgcn_mfma_f32_32x32x16_bf16(ac0, B1[k], acc01, 0, 0, 0);
        acc10 = __builtin_amdgcn_mfma_f32_32x32x16_bf16(ac1, B0[k], acc10, 0, 0, 0);
        acc11 = __builtin_amdgcn_mfma_f32_32x32x16_bf16(ac1, B1[k], acc11, 0, 0, 0);
        // rotate A pipeline
        ac0 = an0; ac1 = an1;
        an0 = af0; an1 = af1;
    }

    // ---- epilogue: bias + partial min (2 oc/lane) -> LDS transpose -> min
    __syncthreads();                  // all xt reads done; overlay as sm
    float* sm = (float*)xt;           // [128 px][65] floats = 33280 B
    const float bv0 = bg[nh * 64 + l31];
    const float bv1 = bg[nh * 64 + 32 + l31];
    #pragma unroll
    for (int reg = 0; reg < 16; ++reg) {
        // D layout (32x32): n = lane&31, m = (reg&3) + 8*(reg>>2) + 4*hi
        const int m = (reg & 3) + 8 * (reg >> 2) + 4 * hi;
        float p0 = fminf(acc00[reg] + bv0, acc01[reg] + bv1);
        float p1 = fminf(acc10[reg] + bv0, acc11[reg] + bv1);
        sm[(r * 64 + m) * 65 + nh * 32 + l31]      = p0;
        sm[(r * 64 + 32 + m) * 65 + nh * 32 + l31] = p1;
    }
    __syncthreads();
    {
        const int px = tid >> 1, half = tid & 1;   // px 0..127
        const float* rowp = sm + px * 65 + half * 32;
        float v = rowp[0];
        #pragma unroll
        for (int j = 1; j < 32; ++j) v = fminf(v, rowp[j]);
        v = fminf(v, __shfl_xor(v, 1, 64));
        if (half == 0) {
            v = tanhf(tanhf(v));
            const int ow = ow0 + (px & 63);
            const int oh = oh0 + (px >> 6);
            if (ow < 254)
                out[((size_t)b * 254 + oh) * 254 + ow] = v;
        }
    }
}

extern "C" void kernel_launch(void* const* d_in, const int* in_sizes, int n_in,
                              void* d_out, int out_size, void* d_ws, size_t ws_size,
                              hipStream_t stream) {
    const float* x  = (const float*)d_in[0];   // (16,64,256,256)
    const float* wg = (const float*)d_in[1];   // (128,64,3,3)
    const float* bs = (const float*)d_in[2];   // (128,)
    float* out = (float*)d_out;                // (16,1,254,254)
    short* wsB = (short*)d_ws;                 // needs 147456 B

    wtrans<<<72, 256, 0, stream>>>(wg, wsB);
    dim3 grid(4, 127, 16);   // ow tiles, oh pairs, batch
    conv_min_tanh_mfma<<<grid, 256, 0, stream>>>(x, wsB, bs, out);
}

// Round 3
// 472.579 us; speedup vs baseline: 2.7721x; 2.7721x over previous
//
#include <hip/hip_runtime.h>
#include <math.h>

// Fused Conv2d(64->128,3x3,valid) + bias + min(oc) + tanh(tanh()) via
// bf16 MFMA implicit GEMM (mfma_f32_32x32x16_bf16).
//
// Round 8: intra-block stage/compute overlap (4-chunk software pipeline).
//  - x-stage split into 4 chunks by icc (8 LDS groups each). K-loop
//    reordered as for(icc){for(tap)} — same accumulation set.
//  - Pipeline: issue c0+c1 loads -> write c0 -> barrier ->
//      sub-loop icc=0 (9 ksteps, 36 MFMAs) with c2 loads in flight ->
//      write c1 -> barrier -> sub-loop icc=1 (c3 in flight) -> ...
//    Only chunk0's HBM latency is exposed; the rest hides under MFMAs.
//  - B: distance-2 register pipeline (prefetch crosses icc boundaries).
//  - A: distance-1 ds_read_b128 pipeline, re-primed per sub-loop.
//  - launch_bounds(256,3): VGPR cap ~170; est. peak ~165 (2x24 load banks
//    + 64 acc + pipes). Round-7 lesson: cap is 512/waves_per_SIMD.
// Block: 256 thr = 4 waves; tile 2 rows x 64 cols x 128 oc.
// LDS: xt[(row*8 + icc*2 + hi)][col66][j8] bf16 = 33792 B.
// Epilogue: LDS transpose (sm[128][65] overlay) + row-min + shfl_xor.

typedef __attribute__((ext_vector_type(8))) short bf16x8;
typedef __attribute__((ext_vector_type(16))) float f32x16;

static __device__ __forceinline__ short f2bf(float f) {
    unsigned u = __float_as_uint(f);
    u += 0x7fffu + ((u >> 16) & 1u);
    return (short)(u >> 16);
}

// v_cvt_pk_bf16_f32: D[15:0]=bf16(a), D[31:16]=bf16(b), round-nearest-even.
static __device__ __forceinline__ unsigned cvt_pk_bf16(float a, float b) {
    unsigned r;
    asm("v_cvt_pk_bf16_f32 %0, %1, %2" : "=v"(r) : "v"(a), "v"(b));
    return r;
}

// d_ws layout: bf16 bits, idx = ((kstep*2 + hi)*128 + oc)*8 + j
// kstep = tap*4 + icc, tap = kh*3 + kw, ic = icc*16 + hi*8 + j. 73728 elems.
__global__ void wtrans(const float* __restrict__ wg, short* __restrict__ wsB) {
    int o4 = blockIdx.x * 256 + threadIdx.x;   // 0..18431 (x4 elements)
    if (o4 >= 18432) return;
    float4 v = ((const float4*)wg)[o4];        // coalesced read
    float f[4] = {v.x, v.y, v.z, v.w};
    int base = o4 * 4;
    #pragma unroll
    for (int q = 0; q < 4; ++q) {
        int e  = base + q;                     // ((oc*64+ic)*3+kh)*3+kw
        int kw = e % 3, r1 = e / 3;
        int kh = r1 % 3, r2 = r1 / 3;
        int ic = r2 & 63, oc = r2 >> 6;
        int tap = kh * 3 + kw;
        int icc = ic >> 4, hi = (ic >> 3) & 1, j = ic & 7;
        int kstep = tap * 4 + icc;
        wsB[((kstep * 2 + hi) * 128 + oc) * 8 + j] = f2bf(f[q]);
    }
}

// Stage chunk c (icc=c): 8 groups x 66 cols = 528 bf16x8 vectors.
// Thread handles v = s*256+tid (s=0..2, v<528).
#define STAGE_ISSUE(c, f)                                                     \
    _Pragma("unroll")                                                         \
    for (int s = 0; s < 3; ++s) {                                             \
        int v = s * 256 + tid;                                                \
        if (v < 528) {                                                        \
            int gl = v / 66, col = v - gl * 66;                               \
            int row = gl >> 1, hie = gl & 1;                                  \
            int iw = ow0 + col;                                               \
            const float* src = xg +                                           \
                (((size_t)(b * 64 + (c) * 16 + hie * 8) * 256) +              \
                 (oh0 + row)) * 256 + iw;                                     \
            bool valid = iw < 256;                                            \
            _Pragma("unroll")                                                 \
            for (int j = 0; j < 8; ++j) f[s][j] = valid ? src[j * 65536] : 0.f; \
        }                                                                     \
    }

#define STAGE_WRITE(c, f)                                                     \
    _Pragma("unroll")                                                         \
    for (int s = 0; s < 3; ++s) {                                             \
        int v = s * 256 + tid;                                                \
        if (v < 528) {                                                        \
            int gl = v / 66, col = v - gl * 66;                               \
            int row = gl >> 1, hie = gl & 1;                                  \
            bf16x8 vv;                                                        \
            unsigned* vp = (unsigned*)&vv;                                    \
            _Pragma("unroll")                                                 \
            for (int p = 0; p < 4; ++p)                                       \
                vp[p] = cvt_pk_bf16(f[s][2 * p], f[s][2 * p + 1]);            \
            *(bf16x8*)(xt + (row * 8 + (c) * 2 + hie) * 528 + col * 8) = vv;  \
        }                                                                     \
    }

__global__ __launch_bounds__(256, 3)
void conv_min_tanh_mfma(const float* __restrict__ xg,
                        const short* __restrict__ wsB,
                        const float* __restrict__ bg,
                        float* __restrict__ out) {
    __shared__ __align__(16) short xt[16896];  // [32 g][66 col][8 j] = 33792 B

    const int tid  = threadIdx.x;
    const int lane = tid & 63, l31 = lane & 31, hi = lane >> 5;
    const int w    = tid >> 6;
    const int r    = w & 1;        // output row within pair
    const int nh   = w >> 1;       // oc half
    const int ow0  = blockIdx.x * 64;
    const int oh0  = blockIdx.y * 2;
    const int b    = blockIdx.z;

    // ---- B pipeline preload for sub-loop icc=0: k=0 (tap0) and k=4 (tap1).
    // Issued first; latency hides under the x staging below.
    const bf16x8* bbase = (const bf16x8*)(wsB + ((size_t)hi * 128 + nh * 64 + l31) * 8);
    bf16x8 bc0 = bbase[0],       bc1 = bbase[32];
    bf16x8 bd0 = bbase[4 * 256], bd1 = bbase[4 * 256 + 32];

    // ---- stage pipeline: issue chunk0+1, write chunk0, barrier.
    float fA[3][8], fB[3][8];
    STAGE_ISSUE(0, fA)
    STAGE_ISSUE(1, fB)
    STAGE_WRITE(0, fA)
    __syncthreads();               // chunk0 readable

    f32x16 acc00 = {}, acc01 = {}, acc10 = {}, acc11 = {};

    #pragma unroll
    for (int icc = 0; icc < 4; ++icc) {
        // issue next+1 chunk's global loads (in flight across this sub-loop)
        if (icc == 0) { STAGE_ISSUE(2, fA) }
        if (icc == 1) { STAGE_ISSUE(3, fB) }

        // A pipeline prime for tap 0 (kh=kw=0) of this icc
        const bf16x8* ap = (const bf16x8*)(xt + ((r * 4 + icc) * 2 + hi) * 528 + l31 * 8);
        bf16x8 a0 = ap[0], a1 = ap[32];

        #pragma unroll
        for (int t = 0; t < 9; ++t) {
            // A prefetch for tap t+1 (same icc)
            bf16x8 an0 = a0, an1 = a1;
            if (t < 8) {
                const int tapn = t + 1, khn = tapn / 3, kwn = tapn - khn * 3;
                const bf16x8* apn = (const bf16x8*)(xt +
                    (((r + khn) * 4 + icc) * 2 + hi) * 528 + (l31 + kwn) * 8);
                an0 = apn[0];
                an1 = apn[32];
            }
            // B prefetch distance 2 (crosses into next icc at t=7,8)
            bf16x8 be0 = bd0, be1 = bd1;
            if (t < 7) {
                const int kp = (t + 2) * 4 + icc;
                be0 = bbase[kp * 256];
                be1 = bbase[kp * 256 + 32];
            } else if (icc < 3) {
                const int kp = (t - 7) * 4 + icc + 1;
                be0 = bbase[kp * 256];
                be1 = bbase[kp * 256 + 32];
            }
            acc00 = __builtin_amdgcn_mfma_f32_32x32x16_bf16(a0, bc0, acc00, 0, 0, 0);
            acc01 = __builtin_amdgcn_mfma_f32_32x32x16_bf16(a0, bc1, acc01, 0, 0, 0);
            acc10 = __builtin_amdgcn_mfma_f32_32x32x16_bf16(a1, bc0, acc10, 0, 0, 0);
            acc11 = __builtin_amdgcn_mfma_f32_32x32x16_bf16(a1, bc1, acc11, 0, 0, 0);
            // rotate pipelines
            a0 = an0; a1 = an1;
            bc0 = bd0; bc1 = bd1;
            bd0 = be0; bd1 = be1;
        }

        // write next chunk + barrier (not after the last sub-loop)
        if (icc == 0) { STAGE_WRITE(1, fB) __syncthreads(); }
        if (icc == 1) { STAGE_WRITE(2, fA) __syncthreads(); }
        if (icc == 2) { STAGE_WRITE(3, fB) __syncthreads(); }
    }

    // ---- epilogue: bias + partial min (2 oc/lane) -> LDS transpose -> min
    __syncthreads();                  // all xt reads done; overlay as sm
    float* sm = (float*)xt;           // [128 px][65] floats = 33280 B
    const float bv0 = bg[nh * 64 + l31];
    const float bv1 = bg[nh * 64 + 32 + l31];
    #pragma unroll
    for (int reg = 0; reg < 16; ++reg) {
        // D layout (32x32): n = lane&31, m = (reg&3) + 8*(reg>>2) + 4*hi
        const int m = (reg & 3) + 8 * (reg >> 2) + 4 * hi;
        float p0 = fminf(acc00[reg] + bv0, acc01[reg] + bv1);
        float p1 = fminf(acc10[reg] + bv0, acc11[reg] + bv1);
        sm[(r * 64 + m) * 65 + nh * 32 + l31]      = p0;
        sm[(r * 64 + 32 + m) * 65 + nh * 32 + l31] = p1;
    }
    __syncthreads();
    {
        const int px = tid >> 1, half = tid & 1;   // px 0..127
        const float* rowp = sm + px * 65 + half * 32;
        float v = rowp[0];
        #pragma unroll
        for (int j = 1; j < 32; ++j) v = fminf(v, rowp[j]);
        v = fminf(v, __shfl_xor(v, 1, 64));
        if (half == 0) {
            v = tanhf(tanhf(v));
            const int ow = ow0 + (px & 63);
            const int oh = oh0 + (px >> 6);
            if (ow < 254)
                out[((size_t)b * 254 + oh) * 254 + ow] = v;
        }
    }
}

extern "C" void kernel_launch(void* const* d_in, const int* in_sizes, int n_in,
                              void* d_out, int out_size, void* d_ws, size_t ws_size,
                              hipStream_t stream) {
    const float* x  = (const float*)d_in[0];   // (16,64,256,256)
    const float* wg = (const float*)d_in[1];   // (128,64,3,3)
    const float* bs = (const float*)d_in[2];   // (128,)
    float* out = (float*)d_out;                // (16,1,254,254)
    short* wsB = (short*)d_ws;                 // needs 147456 B

    wtrans<<<72, 256, 0, stream>>>(wg, wsB);
    dim3 grid(4, 127, 16);   // ow tiles, oh pairs, batch
    conv_min_tanh_mfma<<<grid, 256, 0, stream>>>(x, wsB, bs, out);
}